// Round 2
// baseline (668.101 us; speedup 1.0000x reference)
//
#include <hip/hip_runtime.h>

// xLSTMCell fused: B=4096, D_IN=H=1024, 6 gates. Inputs/outputs are FLOAT32
// (reference dtype); MFMA runs bf16 16x16x32 with fp32 accum (threshold 9.75e-2
// permits bf16 compute). fp32 global -> cvt bf16 -> LDS -> MFMA.
// Block tile 128x128 over [B,H]; 512 threads = 8 waves, each wave 64x32.
// 12 sequential K=1024 GEMM passes per tile, 3 live accumulator sets.

#define B_DIM 4096
#define K_DIM 1024
#define H_DIM 1024

constexpr int BM = 128, BN = 128, BK = 64;
constexpr int LDS_STRIDE = BK + 8;  // 72 elems = 144 B rows; 144%16==0 keeps b128 aligned

using f32x4  = __attribute__((ext_vector_type(4))) float;
using bf16x8 = __attribute__((ext_vector_type(8))) __bf16;
using u16x4  = __attribute__((ext_vector_type(4))) unsigned short;

__device__ __forceinline__ unsigned short f2bf(float f) {
    union { float f; unsigned int i; } v; v.f = f;
    unsigned int r = v.i + 0x7fffu + ((v.i >> 16) & 1u);  // round-nearest-even
    return (unsigned short)(r >> 16);
}
__device__ __forceinline__ float sigm(float x) { return 1.f / (1.f + __expf(-x)); }
__device__ __forceinline__ float tanh_fast(float x) {
    float ax = fminf(fabsf(x), 15.f);          // clamp: avoids inf/inf
    float e  = __expf(2.f * ax);
    float t  = (e - 1.f) / (e + 1.f);
    return copysignf(t, x);
}

// One full K=1024 NT-GEMM pass accumulating into acc[4][2] (wave tile 64x32).
// Ag: [*, K_DIM] fp32 rows of x/h tile base; Bg: [*, K_DIM] fp32 rows of W/U tile base.
__device__ __forceinline__ void mm_pass(const float* __restrict__ Ag,
                                        const float* __restrict__ Bg,
                                        unsigned short* lA, unsigned short* lB,
                                        int st_r, int st_c, int wm, int wn, int frow, int fk,
                                        f32x4 acc[4][2])
{
    for (int k0 = 0; k0 < K_DIM; k0 += BK) {
        // stage 128x64 fp32 -> bf16 for A and B; each thread 4 rows x 4 elems per matrix
#pragma unroll
        for (int q = 0; q < 4; ++q) {
            const int r = st_r + 32 * q;
            f32x4 av = *(const f32x4*)&Ag[(size_t)r * K_DIM + k0 + st_c];
            f32x4 bv = *(const f32x4*)&Bg[(size_t)r * K_DIM + k0 + st_c];
            u16x4 ap = { f2bf(av[0]), f2bf(av[1]), f2bf(av[2]), f2bf(av[3]) };
            u16x4 bp = { f2bf(bv[0]), f2bf(bv[1]), f2bf(bv[2]), f2bf(bv[3]) };
            *(u16x4*)&lA[r * LDS_STRIDE + st_c] = ap;
            *(u16x4*)&lB[r * LDS_STRIDE + st_c] = bp;
        }
        __syncthreads();
#pragma unroll
        for (int kk = 0; kk < BK; kk += 32) {
            bf16x8 bfr0 = *(const bf16x8*)&lB[(wn      + frow) * LDS_STRIDE + kk + fk];
            bf16x8 bfr1 = *(const bf16x8*)&lB[(wn + 16 + frow) * LDS_STRIDE + kk + fk];
#pragma unroll
            for (int mi = 0; mi < 4; ++mi) {
                bf16x8 afr = *(const bf16x8*)&lA[(wm + mi * 16 + frow) * LDS_STRIDE + kk + fk];
                acc[mi][0] = __builtin_amdgcn_mfma_f32_16x16x32_bf16(afr, bfr0, acc[mi][0], 0, 0, 0);
                acc[mi][1] = __builtin_amdgcn_mfma_f32_16x16x32_bf16(afr, bfr1, acc[mi][1], 0, 0, 0);
            }
        }
        __syncthreads();
    }
}

extern "C" __global__ __launch_bounds__(512, 2)
void xlstm_fused(const float* __restrict__ x,
                 const float* __restrict__ h_prev,
                 const float* __restrict__ c_prev,
                 const float* __restrict__ W_all,
                 const float* __restrict__ b_all,
                 const float* __restrict__ U_all,
                 float* __restrict__ out)
{
    __shared__ unsigned short lA[BM * LDS_STRIDE];
    __shared__ unsigned short lB[BN * LDS_STRIDE];

    const int tid  = threadIdx.x;
    const int bm   = blockIdx.y * BM;   // batch offset
    const int bn   = blockIdx.x * BN;   // hidden offset
    const int st_r = tid >> 4;          // staging row 0..31
    const int st_c = (tid & 15) * 4;    // staging col (float4 chunks)
    const int lane = tid & 63;
    const int wave = tid >> 6;          // 0..7
    const int wm   = (wave & 1) * 64;   // wave row offset in tile
    const int wn   = (wave >> 1) * 32;  // wave col offset in tile
    const int frow = lane & 15;         // fragment row (m or n index)
    const int fk   = (lane >> 4) * 8;   // fragment k offset
    const int col  = lane & 15;         // C/D col within 16x16 frag
    const int rbase = (lane >> 4) * 4;  // C/D row base within 16x16 frag

    const float* Axt = x      + (size_t)bm * K_DIM;
    const float* Aht = h_prev + (size_t)bm * K_DIM;

    f32x4 acc[4][2], s1[4][2], s2[4][2];

    // gate indices in reference order: i=0, f=1, o=2, g=3, mul=4, a=5
#define WG(g) (W_all + (size_t)(g) * H_DIM * K_DIM + (size_t)bn * K_DIM)
#define UG(g) (U_all + (size_t)(g) * H_DIM * H_DIM + (size_t)bn * H_DIM)
#define SET_BIAS(g) do {                                                        \
        float bv0 = b_all[(g) * H_DIM + bn + wn + col];                         \
        float bv1 = b_all[(g) * H_DIM + bn + wn + 16 + col];                    \
        _Pragma("unroll") for (int mi = 0; mi < 4; ++mi) {                      \
            acc[mi][0] = (f32x4){bv0, bv0, bv0, bv0};                           \
            acc[mi][1] = (f32x4){bv1, bv1, bv1, bv1};                           \
        }                                                                       \
    } while (0)
#define RUN_GATE(g) do {                                                        \
        SET_BIAS(g);                                                            \
        mm_pass(Axt, WG(g), lA, lB, st_r, st_c, wm, wn, frow, fk, acc);         \
        mm_pass(Aht, UG(g), lA, lB, st_r, st_c, wm, wn, frow, fk, acc);         \
    } while (0)

    // ---- 1) wx4 (with bias b4) ----
    SET_BIAS(4);
    mm_pass(Axt, WG(4), lA, lB, st_r, st_c, wm, wn, frow, fk, acc);
#pragma unroll
    for (int mi = 0; mi < 4; ++mi)
#pragma unroll
        for (int ni = 0; ni < 2; ++ni) s1[mi][ni] = acc[mi][ni];

    // ---- 2) uh4 (no bias): s1 = m = wx4 * uh4 ----
#pragma unroll
    for (int mi = 0; mi < 4; ++mi)
#pragma unroll
        for (int ni = 0; ni < 2; ++ni) acc[mi][ni] = (f32x4){0.f, 0.f, 0.f, 0.f};
    mm_pass(Aht, UG(4), lA, lB, st_r, st_c, wm, wn, frow, fk, acc);
#pragma unroll
    for (int mi = 0; mi < 4; ++mi)
#pragma unroll
        for (int ni = 0; ni < 2; ++ni) s1[mi][ni] *= acc[mi][ni];

    // ---- 3) a-gate (5): s1 = sigmoid(z_a) * m ----
    RUN_GATE(5);
#pragma unroll
    for (int mi = 0; mi < 4; ++mi)
#pragma unroll
        for (int ni = 0; ni < 2; ++ni)
#pragma unroll
            for (int r = 0; r < 4; ++r) s1[mi][ni][r] = sigm(acc[mi][ni][r]) * s1[mi][ni][r];

    // ---- 4) f-gate (1): s2 = sigmoid(z_f)*c_prev + s1 ----
    RUN_GATE(1);
#pragma unroll
    for (int mi = 0; mi < 4; ++mi)
#pragma unroll
        for (int ni = 0; ni < 2; ++ni)
#pragma unroll
            for (int r = 0; r < 4; ++r) {
                int rg = bm + wm + mi * 16 + rbase + r;
                int cg = bn + wn + ni * 16 + col;
                float cp = c_prev[(size_t)rg * H_DIM + cg];
                s2[mi][ni][r] = sigm(acc[mi][ni][r]) * cp + s1[mi][ni][r];
            }

    // ---- 5) i-gate (0): s1 = sigmoid(z_i) ----
    RUN_GATE(0);
#pragma unroll
    for (int mi = 0; mi < 4; ++mi)
#pragma unroll
        for (int ni = 0; ni < 2; ++ni)
#pragma unroll
            for (int r = 0; r < 4; ++r) s1[mi][ni][r] = sigm(acc[mi][ni][r]);

    // ---- 6) g-gate (3): s2 += i * tanh(z_g) ----
    RUN_GATE(3);
#pragma unroll
    for (int mi = 0; mi < 4; ++mi)
#pragma unroll
        for (int ni = 0; ni < 2; ++ni)
#pragma unroll
            for (int r = 0; r < 4; ++r) s2[mi][ni][r] += s1[mi][ni][r] * tanh_fast(acc[mi][ni][r]);

    // ---- 7) o-gate (2): h = sigmoid(z_o) * tanh(c_new); store fp32 ----
    RUN_GATE(2);
#pragma unroll
    for (int mi = 0; mi < 4; ++mi)
#pragma unroll
        for (int ni = 0; ni < 2; ++ni)
#pragma unroll
            for (int r = 0; r < 4; ++r) {
                int rg = bm + wm + mi * 16 + rbase + r;
                int cg = bn + wn + ni * 16 + col;
                float cn = s2[mi][ni][r];
                float hv = sigm(acc[mi][ni][r]) * tanh_fast(cn);
                out[(size_t)rg * H_DIM + cg] = hv;
                out[(size_t)B_DIM * H_DIM + (size_t)rg * H_DIM + cg] = cn;
            }
#undef WG
#undef UG
#undef SET_BIAS
#undef RUN_GATE
}

extern "C" void kernel_launch(void* const* d_in, const int* in_sizes, int n_in,
                              void* d_out, int out_size, void* d_ws, size_t ws_size,
                              hipStream_t stream)
{
    (void)in_sizes; (void)n_in; (void)out_size; (void)d_ws; (void)ws_size;
    const float* x      = (const float*)d_in[0];
    const float* h_prev = (const float*)d_in[1];
    const float* c_prev = (const float*)d_in[2];
    const float* W_all  = (const float*)d_in[3];
    const float* b_all  = (const float*)d_in[4];
    const float* U_all  = (const float*)d_in[5];
    float* out = (float*)d_out;

    dim3 grid(H_DIM / BN, B_DIM / BM);  // (8, 32) = 256 blocks
    hipLaunchKernelGGL(xlstm_fused, grid, dim3(512), 0, stream,
                       x, h_prev, c_prev, W_all, b_all, U_all, out);
}

// Round 3
// 420.562 us; speedup vs baseline: 1.5886x; 1.5886x over previous
//
#include <hip/hip_runtime.h>

// xLSTMCell fused, round 3. B=4096, D_IN=H=1024, 6 gates, fp32 in/out.
// Plan: (K1) convert x,h,W,U fp32->bf16 into d_ws (40 MB);
//       (K2) main GEMM: BM=128,BN=64, gate-paired stages (2 gates share one
//            A-stream), global_load_lds(16B) staging, LDS double-buffer with
//            ONE barrier per k0, grid (32,16)=512 blocks -> 2 blocks/CU.
// Fallback: round-2 fp32-staging kernel if ws_size < 40 MB.

#define B_DIM 4096
#define K_DIM 1024
#define H_DIM 1024

using f32x4  = __attribute__((ext_vector_type(4))) float;
using bf16x8 = __attribute__((ext_vector_type(8))) __bf16;
using u16x4  = __attribute__((ext_vector_type(4))) unsigned short;

__device__ __forceinline__ unsigned short f2bf(float f) {
    union { float f; unsigned int i; } v; v.f = f;
    unsigned int r = v.i + 0x7fffu + ((v.i >> 16) & 1u);  // RNE
    return (unsigned short)(r >> 16);
}
__device__ __forceinline__ float sigm(float x) { return 1.f / (1.f + __expf(-x)); }
__device__ __forceinline__ float tanh_fast(float x) {
    float ax = fminf(fabsf(x), 15.f);
    float e  = __expf(2.f * ax);
    float t  = (e - 1.f) / (e + 1.f);
    return copysignf(t, x);
}

// ---------------------------------------------------------------- convert ---
// ws layout (u16 elems): x@0 (4194304), h@4194304, W@8388608 (6291456), U@14680064
__global__ __launch_bounds__(256) void cvt_all(const float* __restrict__ x,
                                               const float* __restrict__ h,
                                               const float* __restrict__ W,
                                               const float* __restrict__ U,
                                               unsigned short* __restrict__ ws)
{
    const size_t NX = 1048576, NH = 1048576, NW = 1572864, NU = 1572864;  // float4 units
    const size_t NT = NX + NH + NW + NU;
    size_t i = (size_t)blockIdx.x * blockDim.x + threadIdx.x;
    const size_t step = (size_t)gridDim.x * blockDim.x;
    for (; i < NT; i += step) {
        const float* src; unsigned short* dst; size_t off;
        if      (i < NX)           { src = x; dst = ws;            off = i; }
        else if (i < NX + NH)      { src = h; dst = ws + 4194304;  off = i - NX; }
        else if (i < NX + NH + NW) { src = W; dst = ws + 8388608;  off = i - NX - NH; }
        else                       { src = U; dst = ws + 14680064; off = i - NX - NH - NW; }
        f32x4 v = *(const f32x4*)&src[off * 4];
        u16x4 p = { f2bf(v[0]), f2bf(v[1]), f2bf(v[2]), f2bf(v[3]) };
        *(u16x4*)&dst[off * 4] = p;
    }
}

// ------------------------------------------------------------------- main ---
constexpr int BM = 128, BN = 64, BK = 64;
constexpr int NKB = K_DIM / BK;  // 16

#define GLDS(gp, lp) __builtin_amdgcn_global_load_lds(                          \
        (const __attribute__((address_space(1))) void*)(gp),                    \
        (__attribute__((address_space(3))) void*)(lp), 16, 0, 0)

__global__ __launch_bounds__(512, 4)
void xlstm_main(const unsigned short* __restrict__ xb,
                const unsigned short* __restrict__ hb,
                const unsigned short* __restrict__ Wb,
                const unsigned short* __restrict__ Ub,
                const float* __restrict__ b_all,
                const float* __restrict__ c_prev,
                float* __restrict__ out)
{
    __shared__ unsigned short lA [2][BM * BK];   // 16 KB x2
    __shared__ unsigned short lB0[2][BN * BK];   //  8 KB x2
    __shared__ unsigned short lB1[2][BN * BK];   //  8 KB x2

    const int tid  = threadIdx.x;
    const int lane = tid & 63;
    const int wave = tid >> 6;            // 0..7
    const int bm   = blockIdx.x * BM;     // grid.x = 32 (XCD round-robin over bm)
    const int bn   = blockIdx.y * BN;     // grid.y = 16
    const int wm   = (wave & 3) * 32;
    const int wn   = (wave >> 2) * 32;
    const int frow = lane & 15;
    const int fk   = (lane >> 4) * 8;
    const int col  = lane & 15;
    const int rbase = (lane >> 4) * 4;
    const int srow = lane >> 3;           // 0..7 within chunk
    const int scol = (lane & 7) * 8;      // element col of 16B chunk

    const unsigned short* Ax = xb + (size_t)bm * K_DIM;
    const unsigned short* Ah = hb + (size_t)bm * K_DIM;

    f32x4 accA[2][2], accB[2][2], s1[2][2], s2[2][2], sm[2][2];

    // issue async staging for one k0 into buffer `buf`
    auto issue = [&](const unsigned short* Abase, const unsigned short* B0,
                     const unsigned short* B1, int k0, int buf) {
#pragma unroll
        for (int q = 0; q < 2; ++q) {
            int c = wave + q * 8;                 // chunk 0..15 of A tile
            int r = c * 8 + srow;
            GLDS(Abase + (size_t)r * K_DIM + k0 + scol, &lA[buf][c * 512]);
        }
        {
            int r = wave * 8 + srow;              // chunk = wave for B tiles
            GLDS(B0 + (size_t)r * K_DIM + k0 + scol, &lB0[buf][wave * 512]);
            GLDS(B1 + (size_t)r * K_DIM + k0 + scol, &lB1[buf][wave * 512]);
        }
    };

    auto mmstep = [&](int buf) {
#pragma unroll
        for (int kk = 0; kk < BK; kk += 32) {
            bf16x8 a0  = *(const bf16x8*)&lA [buf][(wm      + frow) * BK + kk + fk];
            bf16x8 a1  = *(const bf16x8*)&lA [buf][(wm + 16 + frow) * BK + kk + fk];
            bf16x8 b00 = *(const bf16x8*)&lB0[buf][(wn      + frow) * BK + kk + fk];
            bf16x8 b01 = *(const bf16x8*)&lB0[buf][(wn + 16 + frow) * BK + kk + fk];
            bf16x8 b10 = *(const bf16x8*)&lB1[buf][(wn      + frow) * BK + kk + fk];
            bf16x8 b11 = *(const bf16x8*)&lB1[buf][(wn + 16 + frow) * BK + kk + fk];
            accA[0][0] = __builtin_amdgcn_mfma_f32_16x16x32_bf16(a0, b00, accA[0][0], 0, 0, 0);
            accA[0][1] = __builtin_amdgcn_mfma_f32_16x16x32_bf16(a0, b01, accA[0][1], 0, 0, 0);
            accA[1][0] = __builtin_amdgcn_mfma_f32_16x16x32_bf16(a1, b00, accA[1][0], 0, 0, 0);
            accA[1][1] = __builtin_amdgcn_mfma_f32_16x16x32_bf16(a1, b01, accA[1][1], 0, 0, 0);
            accB[0][0] = __builtin_amdgcn_mfma_f32_16x16x32_bf16(a0, b10, accB[0][0], 0, 0, 0);
            accB[0][1] = __builtin_amdgcn_mfma_f32_16x16x32_bf16(a0, b11, accB[0][1], 0, 0, 0);
            accB[1][0] = __builtin_amdgcn_mfma_f32_16x16x32_bf16(a1, b10, accB[1][0], 0, 0, 0);
            accB[1][1] = __builtin_amdgcn_mfma_f32_16x16x32_bf16(a1, b11, accB[1][1], 0, 0, 0);
        }
    };

    // one K=1024 paired stage: acc{A,B} += A-stream @ {B0,B1}^T
    auto stage = [&](const unsigned short* Abase, const unsigned short* B0,
                     const unsigned short* B1) {
        __syncthreads();                  // protect buffers from previous stage readers
        issue(Abase, B0, B1, 0, 0);
        int cur = 0;
        for (int k = 0; k < NKB; ++k) {
            __syncthreads();              // drains in-flight loads for buf `cur`
            if (k + 1 < NKB) issue(Abase, B0, B1, (k + 1) * BK, cur ^ 1);
            mmstep(cur);
            cur ^= 1;
        }
    };

#define WG(g) (Wb + (size_t)(g) * H_DIM * K_DIM + (size_t)bn * K_DIM)
#define UG(g) (Ub + (size_t)(g) * H_DIM * H_DIM + (size_t)bn * H_DIM)
#define SET_BIAS(acc, g) do {                                                   \
        float bv0 = b_all[(g) * H_DIM + bn + wn + col];                         \
        float bv1 = b_all[(g) * H_DIM + bn + wn + 16 + col];                    \
        _Pragma("unroll") for (int mi = 0; mi < 2; ++mi) {                      \
            acc[mi][0] = (f32x4){bv0, bv0, bv0, bv0};                           \
            acc[mi][1] = (f32x4){bv1, bv1, bv1, bv1};                           \
        }                                                                       \
    } while (0)

    // ---- S1: gates 4 (mul) and 5 (a) ----
    SET_BIAS(accA, 4); SET_BIAS(accB, 5);
    stage(Ax, WG(4), WG(5));                       // accA=wx4(+b4), accB=b5+xW5
#pragma unroll
    for (int mi = 0; mi < 2; ++mi)
#pragma unroll
        for (int ni = 0; ni < 2; ++ni) { sm[mi][ni] = accA[mi][ni]; accA[mi][ni] = (f32x4){0,0,0,0}; }
    stage(Ah, UG(4), UG(5));                       // accA=uh4, accB=z_a
#pragma unroll
    for (int mi = 0; mi < 2; ++mi)
#pragma unroll
        for (int ni = 0; ni < 2; ++ni)
#pragma unroll
            for (int r = 0; r < 4; ++r)
                s1[mi][ni][r] = sigm(accB[mi][ni][r]) * (sm[mi][ni][r] * accA[mi][ni][r]);

    // ---- S2: gates 1 (f) and 0 (i) ----
    SET_BIAS(accA, 1); SET_BIAS(accB, 0);
    stage(Ax, WG(1), WG(0));
    stage(Ah, UG(1), UG(0));
#pragma unroll
    for (int mi = 0; mi < 2; ++mi)
#pragma unroll
        for (int ni = 0; ni < 2; ++ni)
#pragma unroll
            for (int r = 0; r < 4; ++r) {
                int rg = bm + wm + mi * 16 + rbase + r;
                int cg = bn + wn + ni * 16 + col;
                float cp = c_prev[(size_t)rg * H_DIM + cg];
                s2[mi][ni][r] = sigm(accA[mi][ni][r]) * cp + s1[mi][ni][r];
                s1[mi][ni][r] = sigm(accB[mi][ni][r]);   // i-gate
            }

    // ---- S3: gates 3 (g) and 2 (o) ----
    SET_BIAS(accA, 3); SET_BIAS(accB, 2);
    stage(Ax, WG(3), WG(2));
    stage(Ah, UG(3), UG(2));
#pragma unroll
    for (int mi = 0; mi < 2; ++mi)
#pragma unroll
        for (int ni = 0; ni < 2; ++ni)
#pragma unroll
            for (int r = 0; r < 4; ++r) {
                int rg = bm + wm + mi * 16 + rbase + r;
                int cg = bn + wn + ni * 16 + col;
                float cn = s2[mi][ni][r] + s1[mi][ni][r] * tanh_fast(accA[mi][ni][r]);
                float hv = sigm(accB[mi][ni][r]) * tanh_fast(cn);
                out[(size_t)rg * H_DIM + cg] = hv;
                out[(size_t)B_DIM * H_DIM + (size_t)rg * H_DIM + cg] = cn;
            }
#undef WG
#undef UG
#undef SET_BIAS
}

// ------------------------------------------------- fallback (round-2, fp32) ---
constexpr int FBM = 128, FBN = 128, FBK = 64;
constexpr int FLDS = FBK + 8;

__device__ __forceinline__ void f_mm_pass(const float* __restrict__ Ag,
                                          const float* __restrict__ Bg,
                                          unsigned short* lA, unsigned short* lB,
                                          int st_r, int st_c, int wm, int wn, int frow, int fk,
                                          f32x4 acc[4][2])
{
    for (int k0 = 0; k0 < K_DIM; k0 += FBK) {
#pragma unroll
        for (int q = 0; q < 4; ++q) {
            const int r = st_r + 32 * q;
            f32x4 av = *(const f32x4*)&Ag[(size_t)r * K_DIM + k0 + st_c];
            f32x4 bv = *(const f32x4*)&Bg[(size_t)r * K_DIM + k0 + st_c];
            u16x4 ap = { f2bf(av[0]), f2bf(av[1]), f2bf(av[2]), f2bf(av[3]) };
            u16x4 bp = { f2bf(bv[0]), f2bf(bv[1]), f2bf(bv[2]), f2bf(bv[3]) };
            *(u16x4*)&lA[r * FLDS + st_c] = ap;
            *(u16x4*)&lB[r * FLDS + st_c] = bp;
        }
        __syncthreads();
#pragma unroll
        for (int kk = 0; kk < FBK; kk += 32) {
            bf16x8 bfr0 = *(const bf16x8*)&lB[(wn      + frow) * FLDS + kk + fk];
            bf16x8 bfr1 = *(const bf16x8*)&lB[(wn + 16 + frow) * FLDS + kk + fk];
#pragma unroll
            for (int mi = 0; mi < 4; ++mi) {
                bf16x8 afr = *(const bf16x8*)&lA[(wm + mi * 16 + frow) * FLDS + kk + fk];
                acc[mi][0] = __builtin_amdgcn_mfma_f32_16x16x32_bf16(afr, bfr0, acc[mi][0], 0, 0, 0);
                acc[mi][1] = __builtin_amdgcn_mfma_f32_16x16x32_bf16(afr, bfr1, acc[mi][1], 0, 0, 0);
            }
        }
        __syncthreads();
    }
}

extern "C" __global__ __launch_bounds__(512, 2)
void xlstm_fused_f32(const float* __restrict__ x, const float* __restrict__ h_prev,
                     const float* __restrict__ c_prev, const float* __restrict__ W_all,
                     const float* __restrict__ b_all, const float* __restrict__ U_all,
                     float* __restrict__ out)
{
    __shared__ unsigned short lA[FBM * FLDS];
    __shared__ unsigned short lB[FBN * FLDS];
    const int tid = threadIdx.x;
    const int bm = blockIdx.y * FBM, bn = blockIdx.x * FBN;
    const int st_r = tid >> 4, st_c = (tid & 15) * 4;
    const int lane = tid & 63, wave = tid >> 6;
    const int wm = (wave & 1) * 64, wn = (wave >> 1) * 32;
    const int frow = lane & 15, fk = (lane >> 4) * 8;
    const int col = lane & 15, rbase = (lane >> 4) * 4;
    const float* Axt = x + (size_t)bm * K_DIM;
    const float* Aht = h_prev + (size_t)bm * K_DIM;
    f32x4 acc[4][2], s1[4][2], s2[4][2];
#define WGf(g) (W_all + (size_t)(g) * H_DIM * K_DIM + (size_t)bn * K_DIM)
#define UGf(g) (U_all + (size_t)(g) * H_DIM * H_DIM + (size_t)bn * H_DIM)
#define SET_BIASf(g) do {                                                       \
        float bv0 = b_all[(g) * H_DIM + bn + wn + col];                         \
        float bv1 = b_all[(g) * H_DIM + bn + wn + 16 + col];                    \
        _Pragma("unroll") for (int mi = 0; mi < 4; ++mi) {                      \
            acc[mi][0] = (f32x4){bv0, bv0, bv0, bv0};                           \
            acc[mi][1] = (f32x4){bv1, bv1, bv1, bv1};                           \
        }                                                                       \
    } while (0)
#define RUN_GATEf(g) do { SET_BIASf(g);                                         \
        f_mm_pass(Axt, WGf(g), lA, lB, st_r, st_c, wm, wn, frow, fk, acc);      \
        f_mm_pass(Aht, UGf(g), lA, lB, st_r, st_c, wm, wn, frow, fk, acc); } while (0)
    SET_BIASf(4);
    f_mm_pass(Axt, WGf(4), lA, lB, st_r, st_c, wm, wn, frow, fk, acc);
    for (int mi = 0; mi < 4; ++mi) for (int ni = 0; ni < 2; ++ni) s1[mi][ni] = acc[mi][ni];
    for (int mi = 0; mi < 4; ++mi) for (int ni = 0; ni < 2; ++ni) acc[mi][ni] = (f32x4){0,0,0,0};
    f_mm_pass(Aht, UGf(4), lA, lB, st_r, st_c, wm, wn, frow, fk, acc);
    for (int mi = 0; mi < 4; ++mi) for (int ni = 0; ni < 2; ++ni) s1[mi][ni] *= acc[mi][ni];
    RUN_GATEf(5);
    for (int mi = 0; mi < 4; ++mi) for (int ni = 0; ni < 2; ++ni)
        for (int r = 0; r < 4; ++r) s1[mi][ni][r] = sigm(acc[mi][ni][r]) * s1[mi][ni][r];
    RUN_GATEf(1);
    for (int mi = 0; mi < 4; ++mi) for (int ni = 0; ni < 2; ++ni)
        for (int r = 0; r < 4; ++r) {
            int rg = bm + wm + mi * 16 + rbase + r, cg = bn + wn + ni * 16 + col;
            s2[mi][ni][r] = sigm(acc[mi][ni][r]) * c_prev[(size_t)rg * H_DIM + cg] + s1[mi][ni][r];
        }
    RUN_GATEf(0);
    for (int mi = 0; mi < 4; ++mi) for (int ni = 0; ni < 2; ++ni)
        for (int r = 0; r < 4; ++r) s1[mi][ni][r] = sigm(acc[mi][ni][r]);
    RUN_GATEf(3);
    for (int mi = 0; mi < 4; ++mi) for (int ni = 0; ni < 2; ++ni)
        for (int r = 0; r < 4; ++r) s2[mi][ni][r] += s1[mi][ni][r] * tanh_fast(acc[mi][ni][r]);
    RUN_GATEf(2);
    for (int mi = 0; mi < 4; ++mi) for (int ni = 0; ni < 2; ++ni)
        for (int r = 0; r < 4; ++r) {
            int rg = bm + wm + mi * 16 + rbase + r, cg = bn + wn + ni * 16 + col;
            float cn = s2[mi][ni][r];
            out[(size_t)rg * H_DIM + cg] = sigm(acc[mi][ni][r]) * tanh_fast(cn);
            out[(size_t)B_DIM * H_DIM + (size_t)rg * H_DIM + cg] = cn;
        }
#undef WGf
#undef UGf
#undef SET_BIASf
#undef RUN_GATEf
}

// ------------------------------------------------------------------ launch ---
extern "C" void kernel_launch(void* const* d_in, const int* in_sizes, int n_in,
                              void* d_out, int out_size, void* d_ws, size_t ws_size,
                              hipStream_t stream)
{
    (void)in_sizes; (void)n_in; (void)out_size;
    const float* x      = (const float*)d_in[0];
    const float* h_prev = (const float*)d_in[1];
    const float* c_prev = (const float*)d_in[2];
    const float* W_all  = (const float*)d_in[3];
    const float* b_all  = (const float*)d_in[4];
    const float* U_all  = (const float*)d_in[5];
    float* out = (float*)d_out;

    const size_t need = 20971520ull * 2ull;  // 40 MB of bf16
    if (ws_size >= need) {
        unsigned short* wsb = (unsigned short*)d_ws;
        hipLaunchKernelGGL(cvt_all, dim3(2048), dim3(256), 0, stream,
                           x, h_prev, W_all, U_all, wsb);
        hipLaunchKernelGGL(xlstm_main, dim3(B_DIM / BM, H_DIM / BN), dim3(512), 0, stream,
                           wsb, wsb + 4194304, wsb + 8388608, wsb + 14680064,
                           b_all, c_prev, out);
    } else {
        hipLaunchKernelGGL(xlstm_fused_f32, dim3(H_DIM / FBN, B_DIM / FBM), dim3(512), 0, stream,
                           x, h_prev, c_prev, W_all, b_all, U_all, out);
    }
}

// Round 4
// 391.478 us; speedup vs baseline: 1.7066x; 1.0743x over previous
//
#include <hip/hip_runtime.h>

// xLSTMCell fused, round 4. B=4096, D_IN=H=1024, 6 gates, fp32 in/out.
// (K1) cvt x,h,W,U fp32->bf16 into d_ws (block-range mapped, coalesced).
// (K2) main: BM=128,BN=64, gate-paired stages, global_load_lds(16B) staging
//      with XOR-swizzled source addressing (kills the 16-way LDS bank
//      conflict that padding would have fixed but GLDS forbids),
//      LDS double-buffer, one barrier per k0, grid (32,16)=512 -> 2 blk/CU.

#define B_DIM 4096
#define K_DIM 1024
#define H_DIM 1024

using f32x4  = __attribute__((ext_vector_type(4))) float;
using bf16x8 = __attribute__((ext_vector_type(8))) __bf16;
using u16x4  = __attribute__((ext_vector_type(4))) unsigned short;

__device__ __forceinline__ unsigned short f2bf(float f) {
    union { float f; unsigned int i; } v; v.f = f;
    unsigned int r = v.i + 0x7fffu + ((v.i >> 16) & 1u);  // RNE
    return (unsigned short)(r >> 16);
}
__device__ __forceinline__ float sigm(float x) { return 1.f / (1.f + __expf(-x)); }
__device__ __forceinline__ float tanh_fast(float x) {
    float ax = fminf(fabsf(x), 15.f);
    float e  = __expf(2.f * ax);
    float t  = (e - 1.f) / (e + 1.f);
    return copysignf(t, x);
}

// ---------------------------------------------------------------- convert ---
// ws layout (u16 elems): x@0 (4194304), h@4194304, W@8388608 (6291456), U@14680064
// block ranges (1024 float4 units per block): x 1024, h 1024, W 1536, U 1536
__global__ __launch_bounds__(256) void cvt_all(const float* __restrict__ x,
                                               const float* __restrict__ h,
                                               const float* __restrict__ W,
                                               const float* __restrict__ U,
                                               unsigned short* __restrict__ ws)
{
    const int b = blockIdx.x;
    const float* src; unsigned short* dst; size_t base;
    if      (b < 1024) { src = x; dst = ws;            base = (size_t)b          * 1024; }
    else if (b < 2048) { src = h; dst = ws + 4194304;  base = (size_t)(b - 1024) * 1024; }
    else if (b < 3584) { src = W; dst = ws + 8388608;  base = (size_t)(b - 2048) * 1024; }
    else               { src = U; dst = ws + 14680064; base = (size_t)(b - 3584) * 1024; }
#pragma unroll
    for (int k = 0; k < 4; ++k) {
        size_t u = base + (size_t)k * 256 + threadIdx.x;   // float4 unit
        f32x4 v = *(const f32x4*)&src[u * 4];
        u16x4 p = { f2bf(v[0]), f2bf(v[1]), f2bf(v[2]), f2bf(v[3]) };
        *(u16x4*)&dst[u * 4] = p;
    }
}

// ------------------------------------------------------------------- main ---
constexpr int BM = 128, BN = 64, BK = 64;
constexpr int NKB = K_DIM / BK;  // 16

#define GLDS(gp, lp) __builtin_amdgcn_global_load_lds(                          \
        (const __attribute__((address_space(1))) void*)(gp),                    \
        (__attribute__((address_space(3))) void*)(lp), 16, 0, 0)

__global__ __launch_bounds__(512, 4)
void xlstm_main(const unsigned short* __restrict__ xb,
                const unsigned short* __restrict__ hb,
                const unsigned short* __restrict__ Wb,
                const unsigned short* __restrict__ Ub,
                const float* __restrict__ b_all,
                const float* __restrict__ c_prev,
                float* __restrict__ out)
{
    __shared__ unsigned short lA [2][BM * BK];   // 16 KB x2
    __shared__ unsigned short lB0[2][BN * BK];   //  8 KB x2
    __shared__ unsigned short lB1[2][BN * BK];   //  8 KB x2

    const int tid  = threadIdx.x;
    const int lane = tid & 63;
    const int wave = tid >> 6;            // 0..7
    const int bm   = blockIdx.x * BM;     // grid.x = 32
    const int bn   = blockIdx.y * BN;     // grid.y = 16
    const int wm   = (wave & 3) * 32;
    const int wn   = (wave >> 2) * 32;
    const int frow = lane & 15;
    const int col  = lane & 15;
    const int rbase = (lane >> 4) * 4;
    const int srow = lane >> 3;           // 0..7: row within chunk (staging)
    const int sc   = lane & 7;            // physical chunk slot (staging)
    const int scol_sw = ((sc ^ srow) << 3);  // XOR-swizzled source col (elems)

    const unsigned short* Ax = xb + (size_t)bm * K_DIM;
    const unsigned short* Ah = hb + (size_t)bm * K_DIM;

    f32x4 accA[2][2], accB[2][2], s1[2][2], s2[2][2], sm[2][2];

    // async staging for one k0 into buffer `buf`; XOR-swizzled source cols
    auto issue = [&](const unsigned short* Abase, const unsigned short* B0,
                     const unsigned short* B1, int k0, int buf) {
#pragma unroll
        for (int q = 0; q < 2; ++q) {
            int c = wave + q * 8;                 // chunk 0..15 of A tile
            int r = c * 8 + srow;
            GLDS(Abase + (size_t)r * K_DIM + k0 + scol_sw, &lA[buf][c * 512]);
        }
        {
            int r = wave * 8 + srow;              // chunk = wave for B tiles
            GLDS(B0 + (size_t)r * K_DIM + k0 + scol_sw, &lB0[buf][wave * 512]);
            GLDS(B1 + (size_t)r * K_DIM + k0 + scol_sw, &lB1[buf][wave * 512]);
        }
    };

    auto mmstep = [&](int buf) {
#pragma unroll
        for (int s = 0; s < 2; ++s) {
            // logical col chunk jc = s*4 + (lane>>4); phys = jc ^ (row&7),
            // row&7 == lane&7 for every fragment row (offsets are x16)
            const int co = (((s * 4 + (lane >> 4)) ^ (lane & 7)) << 3);
            bf16x8 a0  = *(const bf16x8*)&lA [buf][(wm      + frow) * BK + co];
            bf16x8 a1  = *(const bf16x8*)&lA [buf][(wm + 16 + frow) * BK + co];
            bf16x8 b00 = *(const bf16x8*)&lB0[buf][(wn      + frow) * BK + co];
            bf16x8 b01 = *(const bf16x8*)&lB0[buf][(wn + 16 + frow) * BK + co];
            bf16x8 b10 = *(const bf16x8*)&lB1[buf][(wn      + frow) * BK + co];
            bf16x8 b11 = *(const bf16x8*)&lB1[buf][(wn + 16 + frow) * BK + co];
            accA[0][0] = __builtin_amdgcn_mfma_f32_16x16x32_bf16(a0, b00, accA[0][0], 0, 0, 0);
            accA[0][1] = __builtin_amdgcn_mfma_f32_16x16x32_bf16(a0, b01, accA[0][1], 0, 0, 0);
            accA[1][0] = __builtin_amdgcn_mfma_f32_16x16x32_bf16(a1, b00, accA[1][0], 0, 0, 0);
            accA[1][1] = __builtin_amdgcn_mfma_f32_16x16x32_bf16(a1, b01, accA[1][1], 0, 0, 0);
            accB[0][0] = __builtin_amdgcn_mfma_f32_16x16x32_bf16(a0, b10, accB[0][0], 0, 0, 0);
            accB[0][1] = __builtin_amdgcn_mfma_f32_16x16x32_bf16(a0, b11, accB[0][1], 0, 0, 0);
            accB[1][0] = __builtin_amdgcn_mfma_f32_16x16x32_bf16(a1, b10, accB[1][0], 0, 0, 0);
            accB[1][1] = __builtin_amdgcn_mfma_f32_16x16x32_bf16(a1, b11, accB[1][1], 0, 0, 0);
        }
    };

    auto stage = [&](const unsigned short* Abase, const unsigned short* B0,
                     const unsigned short* B1) {
        __syncthreads();                  // protect buffers from previous readers
        issue(Abase, B0, B1, 0, 0);
        int cur = 0;
        for (int k = 0; k < NKB; ++k) {
            __syncthreads();              // drains in-flight loads for buf `cur`
            if (k + 1 < NKB) issue(Abase, B0, B1, (k + 1) * BK, cur ^ 1);
            mmstep(cur);
            cur ^= 1;
        }
    };

#define WG(g) (Wb + (size_t)(g) * H_DIM * K_DIM + (size_t)bn * K_DIM)
#define UG(g) (Ub + (size_t)(g) * H_DIM * H_DIM + (size_t)bn * H_DIM)
#define SET_BIAS(acc, g) do {                                                   \
        float bv0 = b_all[(g) * H_DIM + bn + wn + col];                         \
        float bv1 = b_all[(g) * H_DIM + bn + wn + 16 + col];                    \
        _Pragma("unroll") for (int mi = 0; mi < 2; ++mi) {                      \
            acc[mi][0] = (f32x4){bv0, bv0, bv0, bv0};                           \
            acc[mi][1] = (f32x4){bv1, bv1, bv1, bv1};                           \
        }                                                                       \
    } while (0)

    // ---- S1: gates 4 (mul) and 5 (a) ----
    SET_BIAS(accA, 4); SET_BIAS(accB, 5);
    stage(Ax, WG(4), WG(5));                       // accA=wx4(+b4), accB=b5+xW5
#pragma unroll
    for (int mi = 0; mi < 2; ++mi)
#pragma unroll
        for (int ni = 0; ni < 2; ++ni) { sm[mi][ni] = accA[mi][ni]; accA[mi][ni] = (f32x4){0,0,0,0}; }
    stage(Ah, UG(4), UG(5));                       // accA=uh4, accB=z_a
#pragma unroll
    for (int mi = 0; mi < 2; ++mi)
#pragma unroll
        for (int ni = 0; ni < 2; ++ni)
#pragma unroll
            for (int r = 0; r < 4; ++r)
                s1[mi][ni][r] = sigm(accB[mi][ni][r]) * (sm[mi][ni][r] * accA[mi][ni][r]);

    // ---- S2: gates 1 (f) and 0 (i) ----
    SET_BIAS(accA, 1); SET_BIAS(accB, 0);
    stage(Ax, WG(1), WG(0));
    stage(Ah, UG(1), UG(0));
#pragma unroll
    for (int mi = 0; mi < 2; ++mi)
#pragma unroll
        for (int ni = 0; ni < 2; ++ni)
#pragma unroll
            for (int r = 0; r < 4; ++r) {
                int rg = bm + wm + mi * 16 + rbase + r;
                int cg = bn + wn + ni * 16 + col;
                float cp = c_prev[(size_t)rg * H_DIM + cg];
                s2[mi][ni][r] = sigm(accA[mi][ni][r]) * cp + s1[mi][ni][r];
                s1[mi][ni][r] = sigm(accB[mi][ni][r]);   // i-gate
            }

    // ---- S3: gates 3 (g) and 2 (o) ----
    SET_BIAS(accA, 3); SET_BIAS(accB, 2);
    stage(Ax, WG(3), WG(2));
    stage(Ah, UG(3), UG(2));
#pragma unroll
    for (int mi = 0; mi < 2; ++mi)
#pragma unroll
        for (int ni = 0; ni < 2; ++ni)
#pragma unroll
            for (int r = 0; r < 4; ++r) {
                int rg = bm + wm + mi * 16 + rbase + r;
                int cg = bn + wn + ni * 16 + col;
                float cn = s2[mi][ni][r] + s1[mi][ni][r] * tanh_fast(accA[mi][ni][r]);
                float hv = sigm(accB[mi][ni][r]) * tanh_fast(cn);
                out[(size_t)rg * H_DIM + cg] = hv;
                out[(size_t)B_DIM * H_DIM + (size_t)rg * H_DIM + cg] = cn;
            }
#undef WG
#undef UG
#undef SET_BIAS
}

// ------------------------------------------------- fallback (round-2, fp32) ---
constexpr int FBM = 128, FBN = 128, FBK = 64;
constexpr int FLDS = FBK + 8;

__device__ __forceinline__ void f_mm_pass(const float* __restrict__ Ag,
                                          const float* __restrict__ Bg,
                                          unsigned short* lA, unsigned short* lB,
                                          int st_r, int st_c, int wm, int wn, int frow, int fk,
                                          f32x4 acc[4][2])
{
    for (int k0 = 0; k0 < K_DIM; k0 += FBK) {
#pragma unroll
        for (int q = 0; q < 4; ++q) {
            const int r = st_r + 32 * q;
            f32x4 av = *(const f32x4*)&Ag[(size_t)r * K_DIM + k0 + st_c];
            f32x4 bv = *(const f32x4*)&Bg[(size_t)r * K_DIM + k0 + st_c];
            u16x4 ap = { f2bf(av[0]), f2bf(av[1]), f2bf(av[2]), f2bf(av[3]) };
            u16x4 bp = { f2bf(bv[0]), f2bf(bv[1]), f2bf(bv[2]), f2bf(bv[3]) };
            *(u16x4*)&lA[r * FLDS + st_c] = ap;
            *(u16x4*)&lB[r * FLDS + st_c] = bp;
        }
        __syncthreads();
#pragma unroll
        for (int kk = 0; kk < FBK; kk += 32) {
            bf16x8 bfr0 = *(const bf16x8*)&lB[(wn      + frow) * FLDS + kk + fk];
            bf16x8 bfr1 = *(const bf16x8*)&lB[(wn + 16 + frow) * FLDS + kk + fk];
#pragma unroll
            for (int mi = 0; mi < 4; ++mi) {
                bf16x8 afr = *(const bf16x8*)&lA[(wm + mi * 16 + frow) * FLDS + kk + fk];
                acc[mi][0] = __builtin_amdgcn_mfma_f32_16x16x32_bf16(afr, bfr0, acc[mi][0], 0, 0, 0);
                acc[mi][1] = __builtin_amdgcn_mfma_f32_16x16x32_bf16(afr, bfr1, acc[mi][1], 0, 0, 0);
            }
        }
        __syncthreads();
    }
}

extern "C" __global__ __launch_bounds__(512, 2)
void xlstm_fused_f32(const float* __restrict__ x, const float* __restrict__ h_prev,
                     const float* __restrict__ c_prev, const float* __restrict__ W_all,
                     const float* __restrict__ b_all, const float* __restrict__ U_all,
                     float* __restrict__ out)
{
    __shared__ unsigned short lA[FBM * FLDS];
    __shared__ unsigned short lB[FBN * FLDS];
    const int tid = threadIdx.x;
    const int bm = blockIdx.y * FBM, bn = blockIdx.x * FBN;
    const int st_r = tid >> 4, st_c = (tid & 15) * 4;
    const int lane = tid & 63, wave = tid >> 6;
    const int wm = (wave & 1) * 64, wn = (wave >> 1) * 32;
    const int frow = lane & 15, fk = (lane >> 4) * 8;
    const int col = lane & 15, rbase = (lane >> 4) * 4;
    const float* Axt = x + (size_t)bm * K_DIM;
    const float* Aht = h_prev + (size_t)bm * K_DIM;
    f32x4 acc[4][2], s1[4][2], s2[4][2];
#define WGf(g) (W_all + (size_t)(g) * H_DIM * K_DIM + (size_t)bn * K_DIM)
#define UGf(g) (U_all + (size_t)(g) * H_DIM * H_DIM + (size_t)bn * H_DIM)
#define SET_BIASf(g) do {                                                       \
        float bv0 = b_all[(g) * H_DIM + bn + wn + col];                         \
        float bv1 = b_all[(g) * H_DIM + bn + wn + 16 + col];                    \
        _Pragma("unroll") for (int mi = 0; mi < 4; ++mi) {                      \
            acc[mi][0] = (f32x4){bv0, bv0, bv0, bv0};                           \
            acc[mi][1] = (f32x4){bv1, bv1, bv1, bv1};                           \
        }                                                                       \
    } while (0)
#define RUN_GATEf(g) do { SET_BIASf(g);                                         \
        f_mm_pass(Axt, WGf(g), lA, lB, st_r, st_c, wm, wn, frow, fk, acc);      \
        f_mm_pass(Aht, UGf(g), lA, lB, st_r, st_c, wm, wn, frow, fk, acc); } while (0)
    SET_BIASf(4);
    f_mm_pass(Axt, WGf(4), lA, lB, st_r, st_c, wm, wn, frow, fk, acc);
    for (int mi = 0; mi < 4; ++mi) for (int ni = 0; ni < 2; ++ni) s1[mi][ni] = acc[mi][ni];
    for (int mi = 0; mi < 4; ++mi) for (int ni = 0; ni < 2; ++ni) acc[mi][ni] = (f32x4){0,0,0,0};
    f_mm_pass(Aht, UGf(4), lA, lB, st_r, st_c, wm, wn, frow, fk, acc);
    for (int mi = 0; mi < 4; ++mi) for (int ni = 0; ni < 2; ++ni) s1[mi][ni] *= acc[mi][ni];
    RUN_GATEf(5);
    for (int mi = 0; mi < 4; ++mi) for (int ni = 0; ni < 2; ++ni)
        for (int r = 0; r < 4; ++r) s1[mi][ni][r] = sigm(acc[mi][ni][r]) * s1[mi][ni][r];
    RUN_GATEf(1);
    for (int mi = 0; mi < 4; ++mi) for (int ni = 0; ni < 2; ++ni)
        for (int r = 0; r < 4; ++r) {
            int rg = bm + wm + mi * 16 + rbase + r, cg = bn + wn + ni * 16 + col;
            s2[mi][ni][r] = sigm(acc[mi][ni][r]) * c_prev[(size_t)rg * H_DIM + cg] + s1[mi][ni][r];
        }
    RUN_GATEf(0);
    for (int mi = 0; mi < 4; ++mi) for (int ni = 0; ni < 2; ++ni)
        for (int r = 0; r < 4; ++r) s1[mi][ni][r] = sigm(acc[mi][ni][r]);
    RUN_GATEf(3);
    for (int mi = 0; mi < 4; ++mi) for (int ni = 0; ni < 2; ++ni)
        for (int r = 0; r < 4; ++r) s2[mi][ni][r] += s1[mi][ni][r] * tanh_fast(acc[mi][ni][r]);
    RUN_GATEf(2);
    for (int mi = 0; mi < 4; ++mi) for (int ni = 0; ni < 2; ++ni)
        for (int r = 0; r < 4; ++r) {
            int rg = bm + wm + mi * 16 + rbase + r, cg = bn + wn + ni * 16 + col;
            float cn = s2[mi][ni][r];
            out[(size_t)rg * H_DIM + cg] = sigm(acc[mi][ni][r]) * tanh_fast(cn);
            out[(size_t)B_DIM * H_DIM + (size_t)rg * H_DIM + cg] = cn;
        }
#undef WGf
#undef UGf
#undef SET_BIASf
#undef RUN_GATEf
}

// ------------------------------------------------------------------ launch ---
extern "C" void kernel_launch(void* const* d_in, const int* in_sizes, int n_in,
                              void* d_out, int out_size, void* d_ws, size_t ws_size,
                              hipStream_t stream)
{
    (void)in_sizes; (void)n_in; (void)out_size;
    const float* x      = (const float*)d_in[0];
    const float* h_prev = (const float*)d_in[1];
    const float* c_prev = (const float*)d_in[2];
    const float* W_all  = (const float*)d_in[3];
    const float* b_all  = (const float*)d_in[4];
    const float* U_all  = (const float*)d_in[5];
    float* out = (float*)d_out;

    const size_t need = 20971520ull * 2ull;  // 40 MB of bf16
    if (ws_size >= need) {
        unsigned short* wsb = (unsigned short*)d_ws;
        hipLaunchKernelGGL(cvt_all, dim3(5120), dim3(256), 0, stream,
                           x, h_prev, W_all, U_all, wsb);
        hipLaunchKernelGGL(xlstm_main, dim3(B_DIM / BM, H_DIM / BN), dim3(512), 0, stream,
                           wsb, wsb + 4194304, wsb + 8388608, wsb + 14680064,
                           b_all, c_prev, out);
    } else {
        hipLaunchKernelGGL(xlstm_fused_f32, dim3(H_DIM / FBN, B_DIM / FBM), dim3(512), 0, stream,
                           x, h_prev, c_prev, W_all, b_all, U_all, out);
    }
}

// Round 5
// 390.806 us; speedup vs baseline: 1.7095x; 1.0017x over previous
//
#include <hip/hip_runtime.h>

// xLSTMCell fused, round 5. B=4096, D_IN=H=1024, 6 gates, fp32 in/out.
// (K1) cvt x,h,W,U fp32->bf16 into d_ws (16B/lane stores).
// (K2) main: BM=128,BN=64, gate-paired stages, global_load_lds(16B) staging,
//      XOR-swizzled source addressing (0 bank conflicts), LDS double-buffer,
//      one barrier per k0.
//      GRID ORDER: blockIdx.x = bn  -> XCD k hosts bn in {k, k+8}: weight
//      working set 3 MB/XCD fits the 4 MiB per-XCD L2 (R4's bm-fastest order
//      thrashed it: FETCH 314 MB for a 40 MB problem).

#define B_DIM 4096
#define K_DIM 1024
#define H_DIM 1024

using f32x4  = __attribute__((ext_vector_type(4))) float;
using bf16x8 = __attribute__((ext_vector_type(8))) __bf16;
using u16x4  = __attribute__((ext_vector_type(4))) unsigned short;
using u16x8  = __attribute__((ext_vector_type(8))) unsigned short;

__device__ __forceinline__ unsigned short f2bf(float f) {
    union { float f; unsigned int i; } v; v.f = f;
    unsigned int r = v.i + 0x7fffu + ((v.i >> 16) & 1u);  // RNE
    return (unsigned short)(r >> 16);
}
__device__ __forceinline__ float sigm(float x) { return 1.f / (1.f + __expf(-x)); }
__device__ __forceinline__ float tanh_fast(float x) {
    float ax = fminf(fabsf(x), 15.f);
    float e  = __expf(2.f * ax);
    float t  = (e - 1.f) / (e + 1.f);
    return copysignf(t, x);
}

// ---------------------------------------------------------------- convert ---
// ws layout (u16 elems): x@0 (4194304), h@4194304, W@8388608 (6291456), U@14680064
// 2560 blocks, each handles 8192 contiguous floats of its segment.
// ranges: x 512 blocks, h 512, W 768, U 768.
__global__ __launch_bounds__(256) void cvt_all(const float* __restrict__ x,
                                               const float* __restrict__ h,
                                               const float* __restrict__ W,
                                               const float* __restrict__ U,
                                               unsigned short* __restrict__ ws)
{
    const int b = blockIdx.x;
    const float* src; unsigned short* dst; size_t base;
    if      (b < 512)  { src = x; dst = ws;            base = (size_t)b          * 8192; }
    else if (b < 1024) { src = h; dst = ws + 4194304;  base = (size_t)(b - 512)  * 8192; }
    else if (b < 1792) { src = W; dst = ws + 8388608;  base = (size_t)(b - 1024) * 8192; }
    else               { src = U; dst = ws + 14680064; base = (size_t)(b - 1792) * 8192; }
#pragma unroll
    for (int k = 0; k < 4; ++k) {
        size_t f = base + ((size_t)k * 256 + threadIdx.x) * 8;
        f32x4 v0 = *(const f32x4*)&src[f];
        f32x4 v1 = *(const f32x4*)&src[f + 4];
        u16x8 p = { f2bf(v0[0]), f2bf(v0[1]), f2bf(v0[2]), f2bf(v0[3]),
                    f2bf(v1[0]), f2bf(v1[1]), f2bf(v1[2]), f2bf(v1[3]) };
        *(u16x8*)&dst[f] = p;
    }
}

// ------------------------------------------------------------------- main ---
constexpr int BM = 128, BN = 64, BK = 64;
constexpr int NKB = K_DIM / BK;  // 16

#define GLDS(gp, lp) __builtin_amdgcn_global_load_lds(                          \
        (const __attribute__((address_space(1))) void*)(gp),                    \
        (__attribute__((address_space(3))) void*)(lp), 16, 0, 0)

__global__ __launch_bounds__(512, 4)
void xlstm_main(const unsigned short* __restrict__ xb,
                const unsigned short* __restrict__ hb,
                const unsigned short* __restrict__ Wb,
                const unsigned short* __restrict__ Ub,
                const float* __restrict__ b_all,
                const float* __restrict__ c_prev,
                float* __restrict__ out)
{
    __shared__ unsigned short lA [2][BM * BK];   // 16 KB x2
    __shared__ unsigned short lB0[2][BN * BK];   //  8 KB x2
    __shared__ unsigned short lB1[2][BN * BK];   //  8 KB x2

    const int tid  = threadIdx.x;
    const int lane = tid & 63;
    const int wave = tid >> 6;            // 0..7
    const int bn   = blockIdx.x * BN;     // grid.x = 16  (XCD-local weight bands)
    const int bm   = blockIdx.y * BM;     // grid.y = 32
    const int wm   = (wave & 3) * 32;
    const int wn   = (wave >> 2) * 32;
    const int frow = lane & 15;
    const int col  = lane & 15;
    const int rbase = (lane >> 4) * 4;
    const int srow = lane >> 3;           // 0..7: row within chunk (staging)
    const int sc   = lane & 7;            // physical chunk slot (staging)
    const int scol_sw = ((sc ^ srow) << 3);  // XOR-swizzled source col (elems)

    const unsigned short* Ax = xb + (size_t)bm * K_DIM;
    const unsigned short* Ah = hb + (size_t)bm * K_DIM;

    f32x4 accA[2][2], accB[2][2], s1[2][2], s2[2][2], sm[2][2];

    // async staging for one k0 into buffer `buf`; XOR-swizzled source cols
    auto issue = [&](const unsigned short* Abase, const unsigned short* B0,
                     const unsigned short* B1, int k0, int buf) {
#pragma unroll
        for (int q = 0; q < 2; ++q) {
            int c = wave + q * 8;                 // chunk 0..15 of A tile
            int r = c * 8 + srow;
            GLDS(Abase + (size_t)r * K_DIM + k0 + scol_sw, &lA[buf][c * 512]);
        }
        {
            int r = wave * 8 + srow;              // chunk = wave for B tiles
            GLDS(B0 + (size_t)r * K_DIM + k0 + scol_sw, &lB0[buf][wave * 512]);
            GLDS(B1 + (size_t)r * K_DIM + k0 + scol_sw, &lB1[buf][wave * 512]);
        }
    };

    auto mmstep = [&](int buf) {
#pragma unroll
        for (int s = 0; s < 2; ++s) {
            // logical col chunk jc = s*4 + (lane>>4); phys = jc ^ (row&7),
            // row&7 == lane&7 for every fragment row (offsets are x16)
            const int co = (((s * 4 + (lane >> 4)) ^ (lane & 7)) << 3);
            bf16x8 a0  = *(const bf16x8*)&lA [buf][(wm      + frow) * BK + co];
            bf16x8 a1  = *(const bf16x8*)&lA [buf][(wm + 16 + frow) * BK + co];
            bf16x8 b00 = *(const bf16x8*)&lB0[buf][(wn      + frow) * BK + co];
            bf16x8 b01 = *(const bf16x8*)&lB0[buf][(wn + 16 + frow) * BK + co];
            bf16x8 b10 = *(const bf16x8*)&lB1[buf][(wn      + frow) * BK + co];
            bf16x8 b11 = *(const bf16x8*)&lB1[buf][(wn + 16 + frow) * BK + co];
            accA[0][0] = __builtin_amdgcn_mfma_f32_16x16x32_bf16(a0, b00, accA[0][0], 0, 0, 0);
            accA[0][1] = __builtin_amdgcn_mfma_f32_16x16x32_bf16(a0, b01, accA[0][1], 0, 0, 0);
            accA[1][0] = __builtin_amdgcn_mfma_f32_16x16x32_bf16(a1, b00, accA[1][0], 0, 0, 0);
            accA[1][1] = __builtin_amdgcn_mfma_f32_16x16x32_bf16(a1, b01, accA[1][1], 0, 0, 0);
            accB[0][0] = __builtin_amdgcn_mfma_f32_16x16x32_bf16(a0, b10, accB[0][0], 0, 0, 0);
            accB[0][1] = __builtin_amdgcn_mfma_f32_16x16x32_bf16(a0, b11, accB[0][1], 0, 0, 0);
            accB[1][0] = __builtin_amdgcn_mfma_f32_16x16x32_bf16(a1, b10, accB[1][0], 0, 0, 0);
            accB[1][1] = __builtin_amdgcn_mfma_f32_16x16x32_bf16(a1, b11, accB[1][1], 0, 0, 0);
        }
    };

    auto stage = [&](const unsigned short* Abase, const unsigned short* B0,
                     const unsigned short* B1) {
        __syncthreads();                  // protect buffers from previous readers
        issue(Abase, B0, B1, 0, 0);
        int cur = 0;
        for (int k = 0; k < NKB; ++k) {
            __syncthreads();              // drains in-flight loads for buf `cur`
            if (k + 1 < NKB) issue(Abase, B0, B1, (k + 1) * BK, cur ^ 1);
            mmstep(cur);
            cur ^= 1;
        }
    };

#define WG(g) (Wb + (size_t)(g) * H_DIM * K_DIM + (size_t)bn * K_DIM)
#define UG(g) (Ub + (size_t)(g) * H_DIM * H_DIM + (size_t)bn * H_DIM)
#define SET_BIAS(acc, g) do {                                                   \
        float bv0 = b_all[(g) * H_DIM + bn + wn + col];                         \
        float bv1 = b_all[(g) * H_DIM + bn + wn + 16 + col];                    \
        _Pragma("unroll") for (int mi = 0; mi < 2; ++mi) {                      \
            acc[mi][0] = (f32x4){bv0, bv0, bv0, bv0};                           \
            acc[mi][1] = (f32x4){bv1, bv1, bv1, bv1};                           \
        }                                                                       \
    } while (0)

    // ---- S1: gates 4 (mul) and 5 (a) ----
    SET_BIAS(accA, 4); SET_BIAS(accB, 5);
    stage(Ax, WG(4), WG(5));                       // accA=wx4(+b4), accB=b5+xW5
#pragma unroll
    for (int mi = 0; mi < 2; ++mi)
#pragma unroll
        for (int ni = 0; ni < 2; ++ni) { sm[mi][ni] = accA[mi][ni]; accA[mi][ni] = (f32x4){0,0,0,0}; }
    stage(Ah, UG(4), UG(5));                       // accA=uh4, accB=z_a
#pragma unroll
    for (int mi = 0; mi < 2; ++mi)
#pragma unroll
        for (int ni = 0; ni < 2; ++ni)
#pragma unroll
            for (int r = 0; r < 4; ++r)
                s1[mi][ni][r] = sigm(accB[mi][ni][r]) * (sm[mi][ni][r] * accA[mi][ni][r]);

    // ---- S2: gates 1 (f) and 0 (i) ----
    SET_BIAS(accA, 1); SET_BIAS(accB, 0);
    stage(Ax, WG(1), WG(0));
    stage(Ah, UG(1), UG(0));
#pragma unroll
    for (int mi = 0; mi < 2; ++mi)
#pragma unroll
        for (int ni = 0; ni < 2; ++ni)
#pragma unroll
            for (int r = 0; r < 4; ++r) {
                int rg = bm + wm + mi * 16 + rbase + r;
                int cg = bn + wn + ni * 16 + col;
                float cp = c_prev[(size_t)rg * H_DIM + cg];
                s2[mi][ni][r] = sigm(accA[mi][ni][r]) * cp + s1[mi][ni][r];
                s1[mi][ni][r] = sigm(accB[mi][ni][r]);   // i-gate
            }

    // ---- S3: gates 3 (g) and 2 (o) ----
    SET_BIAS(accA, 3); SET_BIAS(accB, 2);
    stage(Ax, WG(3), WG(2));
    stage(Ah, UG(3), UG(2));
#pragma unroll
    for (int mi = 0; mi < 2; ++mi)
#pragma unroll
        for (int ni = 0; ni < 2; ++ni)
#pragma unroll
            for (int r = 0; r < 4; ++r) {
                int rg = bm + wm + mi * 16 + rbase + r;
                int cg = bn + wn + ni * 16 + col;
                float cn = s2[mi][ni][r] + s1[mi][ni][r] * tanh_fast(accA[mi][ni][r]);
                float hv = sigm(accB[mi][ni][r]) * tanh_fast(cn);
                out[(size_t)rg * H_DIM + cg] = hv;
                out[(size_t)B_DIM * H_DIM + (size_t)rg * H_DIM + cg] = cn;
            }
#undef WG
#undef UG
#undef SET_BIAS
}

// ------------------------------------------------- fallback (round-2, fp32) ---
constexpr int FBM = 128, FBN = 128, FBK = 64;
constexpr int FLDS = FBK + 8;

__device__ __forceinline__ void f_mm_pass(const float* __restrict__ Ag,
                                          const float* __restrict__ Bg,
                                          unsigned short* lA, unsigned short* lB,
                                          int st_r, int st_c, int wm, int wn, int frow, int fk,
                                          f32x4 acc[4][2])
{
    for (int k0 = 0; k0 < K_DIM; k0 += FBK) {
#pragma unroll
        for (int q = 0; q < 4; ++q) {
            const int r = st_r + 32 * q;
            f32x4 av = *(const f32x4*)&Ag[(size_t)r * K_DIM + k0 + st_c];
            f32x4 bv = *(const f32x4*)&Bg[(size_t)r * K_DIM + k0 + st_c];
            u16x4 ap = { f2bf(av[0]), f2bf(av[1]), f2bf(av[2]), f2bf(av[3]) };
            u16x4 bp = { f2bf(bv[0]), f2bf(bv[1]), f2bf(bv[2]), f2bf(bv[3]) };
            *(u16x4*)&lA[r * FLDS + st_c] = ap;
            *(u16x4*)&lB[r * FLDS + st_c] = bp;
        }
        __syncthreads();
#pragma unroll
        for (int kk = 0; kk < FBK; kk += 32) {
            bf16x8 bfr0 = *(const bf16x8*)&lB[(wn      + frow) * FLDS + kk + fk];
            bf16x8 bfr1 = *(const bf16x8*)&lB[(wn + 16 + frow) * FLDS + kk + fk];
#pragma unroll
            for (int mi = 0; mi < 4; ++mi) {
                bf16x8 afr = *(const bf16x8*)&lA[(wm + mi * 16 + frow) * FLDS + kk + fk];
                acc[mi][0] = __builtin_amdgcn_mfma_f32_16x16x32_bf16(afr, bfr0, acc[mi][0], 0, 0, 0);
                acc[mi][1] = __builtin_amdgcn_mfma_f32_16x16x32_bf16(afr, bfr1, acc[mi][1], 0, 0, 0);
            }
        }
        __syncthreads();
    }
}

extern "C" __global__ __launch_bounds__(512, 2)
void xlstm_fused_f32(const float* __restrict__ x, const float* __restrict__ h_prev,
                     const float* __restrict__ c_prev, const float* __restrict__ W_all,
                     const float* __restrict__ b_all, const float* __restrict__ U_all,
                     float* __restrict__ out)
{
    __shared__ unsigned short lA[FBM * FLDS];
    __shared__ unsigned short lB[FBN * FLDS];
    const int tid = threadIdx.x;
    const int bm = blockIdx.y * FBM, bn = blockIdx.x * FBN;
    const int st_r = tid >> 4, st_c = (tid & 15) * 4;
    const int lane = tid & 63, wave = tid >> 6;
    const int wm = (wave & 1) * 64, wn = (wave >> 1) * 32;
    const int frow = lane & 15, fk = (lane >> 4) * 8;
    const int col = lane & 15, rbase = (lane >> 4) * 4;
    const float* Axt = x + (size_t)bm * K_DIM;
    const float* Aht = h_prev + (size_t)bm * K_DIM;
    f32x4 acc[4][2], s1[4][2], s2[4][2];
#define WGf(g) (W_all + (size_t)(g) * H_DIM * K_DIM + (size_t)bn * K_DIM)
#define UGf(g) (U_all + (size_t)(g) * H_DIM * H_DIM + (size_t)bn * H_DIM)
#define SET_BIASf(g) do {                                                       \
        float bv0 = b_all[(g) * H_DIM + bn + wn + col];                         \
        float bv1 = b_all[(g) * H_DIM + bn + wn + 16 + col];                    \
        _Pragma("unroll") for (int mi = 0; mi < 4; ++mi) {                      \
            acc[mi][0] = (f32x4){bv0, bv0, bv0, bv0};                           \
            acc[mi][1] = (f32x4){bv1, bv1, bv1, bv1};                           \
        }                                                                       \
    } while (0)
#define RUN_GATEf(g) do { SET_BIASf(g);                                         \
        f_mm_pass(Axt, WGf(g), lA, lB, st_r, st_c, wm, wn, frow, fk, acc);      \
        f_mm_pass(Aht, UGf(g), lA, lB, st_r, st_c, wm, wn, frow, fk, acc); } while (0)
    SET_BIASf(4);
    f_mm_pass(Axt, WGf(4), lA, lB, st_r, st_c, wm, wn, frow, fk, acc);
    for (int mi = 0; mi < 4; ++mi) for (int ni = 0; ni < 2; ++ni) s1[mi][ni] = acc[mi][ni];
    for (int mi = 0; mi < 4; ++mi) for (int ni = 0; ni < 2; ++ni) acc[mi][ni] = (f32x4){0,0,0,0};
    f_mm_pass(Aht, UGf(4), lA, lB, st_r, st_c, wm, wn, frow, fk, acc);
    for (int mi = 0; mi < 4; ++mi) for (int ni = 0; ni < 2; ++ni) s1[mi][ni] *= acc[mi][ni];
    RUN_GATEf(5);
    for (int mi = 0; mi < 4; ++mi) for (int ni = 0; ni < 2; ++ni)
        for (int r = 0; r < 4; ++r) s1[mi][ni][r] = sigm(acc[mi][ni][r]) * s1[mi][ni][r];
    RUN_GATEf(1);
    for (int mi = 0; mi < 4; ++mi) for (int ni = 0; ni < 2; ++ni)
        for (int r = 0; r < 4; ++r) {
            int rg = bm + wm + mi * 16 + rbase + r, cg = bn + wn + ni * 16 + col;
            s2[mi][ni][r] = sigm(acc[mi][ni][r]) * c_prev[(size_t)rg * H_DIM + cg] + s1[mi][ni][r];
        }
    RUN_GATEf(0);
    for (int mi = 0; mi < 4; ++mi) for (int ni = 0; ni < 2; ++ni)
        for (int r = 0; r < 4; ++r) s1[mi][ni][r] = sigm(acc[mi][ni][r]);
    RUN_GATEf(3);
    for (int mi = 0; mi < 4; ++mi) for (int ni = 0; ni < 2; ++ni)
        for (int r = 0; r < 4; ++r) s2[mi][ni][r] += s1[mi][ni][r] * tanh_fast(acc[mi][ni][r]);
    RUN_GATEf(2);
    for (int mi = 0; mi < 4; ++mi) for (int ni = 0; ni < 2; ++ni)
        for (int r = 0; r < 4; ++r) {
            int rg = bm + wm + mi * 16 + rbase + r, cg = bn + wn + ni * 16 + col;
            float cn = s2[mi][ni][r];
            out[(size_t)rg * H_DIM + cg] = sigm(acc[mi][ni][r]) * tanh_fast(cn);
            out[(size_t)B_DIM * H_DIM + (size_t)rg * H_DIM + cg] = cn;
        }
#undef WGf
#undef UGf
#undef SET_BIASf
#undef RUN_GATEf
}

// ------------------------------------------------------------------ launch ---
extern "C" void kernel_launch(void* const* d_in, const int* in_sizes, int n_in,
                              void* d_out, int out_size, void* d_ws, size_t ws_size,
                              hipStream_t stream)
{
    (void)in_sizes; (void)n_in; (void)out_size;
    const float* x      = (const float*)d_in[0];
    const float* h_prev = (const float*)d_in[1];
    const float* c_prev = (const float*)d_in[2];
    const float* W_all  = (const float*)d_in[3];
    const float* b_all  = (const float*)d_in[4];
    const float* U_all  = (const float*)d_in[5];
    float* out = (float*)d_out;

    const size_t need = 20971520ull * 2ull;  // 40 MB of bf16
    if (ws_size >= need) {
        unsigned short* wsb = (unsigned short*)d_ws;
        hipLaunchKernelGGL(cvt_all, dim3(2560), dim3(256), 0, stream,
                           x, h_prev, W_all, U_all, wsb);
        // bn fastest (grid.x) -> per-XCD weight-band locality
        hipLaunchKernelGGL(xlstm_main, dim3(H_DIM / BN, B_DIM / BM), dim3(512), 0, stream,
                           wsb, wsb + 4194304, wsb + 8388608, wsb + 14680064,
                           b_all, c_prev, out);
    } else {
        hipLaunchKernelGGL(xlstm_fused_f32, dim3(H_DIM / FBN, B_DIM / FBM), dim3(512), 0, stream,
                           x, h_prev, c_prev, W_all, b_all, U_all, out);
    }
}

// Round 6
// 255.458 us; speedup vs baseline: 2.6153x; 1.5298x over previous
//
#include <hip/hip_runtime.h>

// xLSTMCell, round 6. B=4096, D_IN=H=1024, 6 gates, fp32 in/out.
// Decomposition (needs ws >= 96 MB):
//   (K1) cvt x,h,W,U fp32->bf16 into ws               (~126 MB traffic)
//   (K2) gemm_z: one m97-style GEMM M=4096 N=6144 K=2048 -> 7 bf16 z-planes
//        planes: 0=z_i 1=z_f 2=z_o 3=z_g 4=z_a 5=wx4(+b4) 6=uh4
//        1536 blocks (3/CU resident), 256 thr, 64x64 wave tiles,
//        single-buffer LDS + global_load_lds(16B) + XOR swizzle (0 conflicts).
//   (K3) combine: elementwise gates -> h_new, c_new    (~104 MB traffic)
// Fallbacks: R5 fused kernel (ws >= 40 MB), R2 fp32-staging kernel (else).

#define B_DIM 4096
#define K_DIM 1024
#define H_DIM 1024

using f32x4  = __attribute__((ext_vector_type(4))) float;
using bf16x8 = __attribute__((ext_vector_type(8))) __bf16;
using u16x4  = __attribute__((ext_vector_type(4))) unsigned short;
using u16x8  = __attribute__((ext_vector_type(8))) unsigned short;

__device__ __forceinline__ unsigned short f2bf(float f) {
    union { float f; unsigned int i; } v; v.f = f;
    unsigned int r = v.i + 0x7fffu + ((v.i >> 16) & 1u);  // RNE
    return (unsigned short)(r >> 16);
}
__device__ __forceinline__ float bf2f(unsigned short u) {
    union { unsigned int i; float f; } v; v.i = ((unsigned int)u) << 16; return v.f;
}
__device__ __forceinline__ float sigm(float x) { return 1.f / (1.f + __expf(-x)); }
__device__ __forceinline__ float tanh_fast(float x) {
    float ax = fminf(fabsf(x), 15.f);
    float e  = __expf(2.f * ax);
    float t  = (e - 1.f) / (e + 1.f);
    return copysignf(t, x);
}

#define GLDS(gp, lp) __builtin_amdgcn_global_load_lds(                          \
        (const __attribute__((address_space(1))) void*)(gp),                    \
        (__attribute__((address_space(3))) void*)(lp), 16, 0, 0)

// ws layout (u16 elems): x@0 (4194304), h@4194304, W@8388608 (6291456),
// U@14680064 (6291456), z planes @20971520, 7 x 4194304 each.
constexpr size_t WS_X = 0, WS_H = 4194304, WS_W = 8388608, WS_U = 14680064;
constexpr size_t WS_Z = 20971520;
constexpr size_t ZPL  = 4194304;

// ---------------------------------------------------------------- convert ---
__global__ __launch_bounds__(256) void cvt_all(const float* __restrict__ x,
                                               const float* __restrict__ h,
                                               const float* __restrict__ W,
                                               const float* __restrict__ U,
                                               unsigned short* __restrict__ ws)
{
    const int b = blockIdx.x;
    const float* src; unsigned short* dst; size_t base;
    if      (b < 512)  { src = x; dst = ws + WS_X; base = (size_t)b          * 8192; }
    else if (b < 1024) { src = h; dst = ws + WS_H; base = (size_t)(b - 512)  * 8192; }
    else if (b < 1792) { src = W; dst = ws + WS_W; base = (size_t)(b - 1024) * 8192; }
    else               { src = U; dst = ws + WS_U; base = (size_t)(b - 1792) * 8192; }
#pragma unroll
    for (int k = 0; k < 4; ++k) {
        size_t f = base + ((size_t)k * 256 + threadIdx.x) * 8;
        f32x4 v0 = *(const f32x4*)&src[f];
        f32x4 v1 = *(const f32x4*)&src[f + 4];
        u16x8 p = { f2bf(v0[0]), f2bf(v0[1]), f2bf(v0[2]), f2bf(v0[3]),
                    f2bf(v1[0]), f2bf(v1[1]), f2bf(v1[2]), f2bf(v1[3]) };
        *(u16x8*)&dst[f] = p;
    }
}

// ------------------------------------------------------------------ gemm_z ---
// grid (48, 32): blockIdx.x = n-tile (gate g = nt>>3, hcol0 = (nt&7)*128),
// blockIdx.y = m-tile. 256 threads, 4 waves in 2x2, wave tile 64x64.
__global__ __launch_bounds__(256, 3)
void gemm_z(const unsigned short* __restrict__ xb,
            const unsigned short* __restrict__ hb,
            const unsigned short* __restrict__ Wb,
            const unsigned short* __restrict__ Ub,
            const float* __restrict__ b_all,
            unsigned short* __restrict__ z)
{
    __shared__ unsigned short lA[128 * 64];   // 16 KB
    __shared__ unsigned short lB[128 * 64];   // 16 KB

    const int tid  = threadIdx.x;
    const int lane = tid & 63;
    const int wave = tid >> 6;            // 0..3
    const int nt   = blockIdx.x;          // 0..47
    const int mt   = blockIdx.y;          // 0..31
    const int g    = nt >> 3;             // gate 0..5
    const int hc0  = (nt & 7) * 128;      // h-col band
    const int m0   = mt * 128;
    const int wm   = (wave & 1) * 64;
    const int wn   = (wave >> 1) * 64;
    const int frow = lane & 15;
    const int colid = lane & 15;
    const int rbase = (lane >> 4) * 4;
    const int srow = lane >> 3;           // 0..7
    const int sc   = lane & 7;
    const int ssw  = ((sc ^ srow) << 3);  // XOR-swizzled source col

    const unsigned short* Ax = xb + (size_t)m0 * K_DIM;
    const unsigned short* Ah = hb + (size_t)m0 * K_DIM;
    const unsigned short* Bw = Wb + ((size_t)g * H_DIM + hc0) * K_DIM;
    const unsigned short* Bu = Ub + ((size_t)g * H_DIM + hc0) * K_DIM;

    f32x4 acc[4][4];
    // bias init (z = b + wx + uh; for gate 4 bias lives in wx4)
#pragma unroll
    for (int ni = 0; ni < 4; ++ni) {
        float bv = b_all[g * H_DIM + hc0 + wn + ni * 16 + colid];
#pragma unroll
        for (int mi = 0; mi < 4; ++mi) acc[mi][ni] = (f32x4){bv, bv, bv, bv};
    }

    auto kloop = [&](const unsigned short* A, const unsigned short* B) {
        for (int k0 = 0; k0 < K_DIM; k0 += 64) {
            __syncthreads();              // protect LDS from previous readers
#pragma unroll
            for (int q = 0; q < 4; ++q) {
                int c = wave * 4 + q;     // chunk 0..15 (8 rows each)
                int r = c * 8 + srow;
                GLDS(A + (size_t)r * K_DIM + k0 + ssw, &lA[c * 512]);
                GLDS(B + (size_t)r * K_DIM + k0 + ssw, &lB[c * 512]);
            }
            __syncthreads();              // wait for loads
#pragma unroll
            for (int s = 0; s < 2; ++s) {
                const int co = (((s * 4 + (lane >> 4)) ^ (lane & 7)) << 3);
                bf16x8 af[4], bf[4];
#pragma unroll
                for (int i = 0; i < 4; ++i) {
                    af[i] = *(const bf16x8*)&lA[(wm + i * 16 + frow) * 64 + co];
                    bf[i] = *(const bf16x8*)&lB[(wn + i * 16 + frow) * 64 + co];
                }
#pragma unroll
                for (int mi = 0; mi < 4; ++mi)
#pragma unroll
                    for (int ni = 0; ni < 4; ++ni)
                        acc[mi][ni] = __builtin_amdgcn_mfma_f32_16x16x32_bf16(
                            af[mi], bf[ni], acc[mi][ni], 0, 0, 0);
            }
        }
    };

    auto store_plane = [&](int p) {
        unsigned short* zp = z + (size_t)p * ZPL;
#pragma unroll
        for (int mi = 0; mi < 4; ++mi)
#pragma unroll
            for (int ni = 0; ni < 4; ++ni)
#pragma unroll
                for (int r = 0; r < 4; ++r) {
                    int row = m0 + wm + mi * 16 + rbase + r;
                    int cc  = hc0 + wn + ni * 16 + colid;
                    zp[(size_t)row * H_DIM + cc] = f2bf(acc[mi][ni][r]);
                }
    };

    kloop(Ax, Bw);                         // x @ W_g^T
    if (g == 4) {
        store_plane(5);                    // wx4 (+b4)
#pragma unroll
        for (int mi = 0; mi < 4; ++mi)
#pragma unroll
            for (int ni = 0; ni < 4; ++ni) acc[mi][ni] = (f32x4){0.f, 0.f, 0.f, 0.f};
    }
    kloop(Ah, Bu);                         // (+) h @ U_g^T
    store_plane(g == 4 ? 6 : (g == 5 ? 4 : g));
}

// ----------------------------------------------------------------- combine ---
__global__ __launch_bounds__(256) void combine(const unsigned short* __restrict__ z,
                                               const float* __restrict__ c_prev,
                                               float* __restrict__ out)
{
    const size_t e = ((size_t)blockIdx.x * 256 + threadIdx.x) * 8;
    u16x8 z0 = *(const u16x8*)&z[0 * ZPL + e];
    u16x8 z1 = *(const u16x8*)&z[1 * ZPL + e];
    u16x8 z2 = *(const u16x8*)&z[2 * ZPL + e];
    u16x8 z3 = *(const u16x8*)&z[3 * ZPL + e];
    u16x8 z4 = *(const u16x8*)&z[4 * ZPL + e];
    u16x8 z5 = *(const u16x8*)&z[5 * ZPL + e];
    u16x8 z6 = *(const u16x8*)&z[6 * ZPL + e];
    float hv[8], cv[8];
#pragma unroll
    for (int j = 0; j < 8; ++j) {
        float iv = sigm(bf2f(z0[j]));
        float fv = sigm(bf2f(z1[j]));
        float ov = sigm(bf2f(z2[j]));
        float gv = tanh_fast(bf2f(z3[j]));
        float av = sigm(bf2f(z4[j]));
        float mv = bf2f(z5[j]) * bf2f(z6[j]);
        float cp = c_prev[e + j];
        float cn = fv * cp + iv * gv + av * mv;
        cv[j] = cn;
        hv[j] = ov * tanh_fast(cn);
    }
#pragma unroll
    for (int j = 0; j < 8; ++j) {
        out[e + j] = hv[j];
        out[(size_t)B_DIM * H_DIM + e + j] = cv[j];
    }
}

// ------------------------------------------ fallback 1 (round-5 fused main) ---
constexpr int BM = 128, BN = 64, BK = 64;
constexpr int NKB = K_DIM / BK;

__global__ __launch_bounds__(512, 4)
void xlstm_main(const unsigned short* __restrict__ xb,
                const unsigned short* __restrict__ hb,
                const unsigned short* __restrict__ Wb,
                const unsigned short* __restrict__ Ub,
                const float* __restrict__ b_all,
                const float* __restrict__ c_prev,
                float* __restrict__ out)
{
    __shared__ unsigned short lA [2][BM * BK];
    __shared__ unsigned short lB0[2][BN * BK];
    __shared__ unsigned short lB1[2][BN * BK];

    const int tid  = threadIdx.x;
    const int lane = tid & 63;
    const int wave = tid >> 6;
    const int bn   = blockIdx.x * BN;
    const int bm   = blockIdx.y * BM;
    const int wm   = (wave & 3) * 32;
    const int wn   = (wave >> 2) * 32;
    const int frow = lane & 15;
    const int col  = lane & 15;
    const int rbase = (lane >> 4) * 4;
    const int srow = lane >> 3;
    const int sc   = lane & 7;
    const int scol_sw = ((sc ^ srow) << 3);

    const unsigned short* Ax = xb + (size_t)bm * K_DIM;
    const unsigned short* Ah = hb + (size_t)bm * K_DIM;

    f32x4 accA[2][2], accB[2][2], s1[2][2], s2[2][2], sm[2][2];

    auto issue = [&](const unsigned short* Abase, const unsigned short* B0,
                     const unsigned short* B1, int k0, int buf) {
#pragma unroll
        for (int q = 0; q < 2; ++q) {
            int c = wave + q * 8;
            int r = c * 8 + srow;
            GLDS(Abase + (size_t)r * K_DIM + k0 + scol_sw, &lA[buf][c * 512]);
        }
        {
            int r = wave * 8 + srow;
            GLDS(B0 + (size_t)r * K_DIM + k0 + scol_sw, &lB0[buf][wave * 512]);
            GLDS(B1 + (size_t)r * K_DIM + k0 + scol_sw, &lB1[buf][wave * 512]);
        }
    };

    auto mmstep = [&](int buf) {
#pragma unroll
        for (int s = 0; s < 2; ++s) {
            const int co = (((s * 4 + (lane >> 4)) ^ (lane & 7)) << 3);
            bf16x8 a0  = *(const bf16x8*)&lA [buf][(wm      + frow) * BK + co];
            bf16x8 a1  = *(const bf16x8*)&lA [buf][(wm + 16 + frow) * BK + co];
            bf16x8 b00 = *(const bf16x8*)&lB0[buf][(wn      + frow) * BK + co];
            bf16x8 b01 = *(const bf16x8*)&lB0[buf][(wn + 16 + frow) * BK + co];
            bf16x8 b10 = *(const bf16x8*)&lB1[buf][(wn      + frow) * BK + co];
            bf16x8 b11 = *(const bf16x8*)&lB1[buf][(wn + 16 + frow) * BK + co];
            accA[0][0] = __builtin_amdgcn_mfma_f32_16x16x32_bf16(a0, b00, accA[0][0], 0, 0, 0);
            accA[0][1] = __builtin_amdgcn_mfma_f32_16x16x32_bf16(a0, b01, accA[0][1], 0, 0, 0);
            accA[1][0] = __builtin_amdgcn_mfma_f32_16x16x32_bf16(a1, b00, accA[1][0], 0, 0, 0);
            accA[1][1] = __builtin_amdgcn_mfma_f32_16x16x32_bf16(a1, b01, accA[1][1], 0, 0, 0);
            accB[0][0] = __builtin_amdgcn_mfma_f32_16x16x32_bf16(a0, b10, accB[0][0], 0, 0, 0);
            accB[0][1] = __builtin_amdgcn_mfma_f32_16x16x32_bf16(a0, b11, accB[0][1], 0, 0, 0);
            accB[1][0] = __builtin_amdgcn_mfma_f32_16x16x32_bf16(a1, b10, accB[1][0], 0, 0, 0);
            accB[1][1] = __builtin_amdgcn_mfma_f32_16x16x32_bf16(a1, b11, accB[1][1], 0, 0, 0);
        }
    };

    auto stage = [&](const unsigned short* Abase, const unsigned short* B0,
                     const unsigned short* B1) {
        __syncthreads();
        issue(Abase, B0, B1, 0, 0);
        int cur = 0;
        for (int k = 0; k < NKB; ++k) {
            __syncthreads();
            if (k + 1 < NKB) issue(Abase, B0, B1, (k + 1) * BK, cur ^ 1);
            mmstep(cur);
            cur ^= 1;
        }
    };

#define WG(g) (Wb + (size_t)(g) * H_DIM * K_DIM + (size_t)bn * K_DIM)
#define UG(g) (Ub + (size_t)(g) * H_DIM * H_DIM + (size_t)bn * H_DIM)
#define SET_BIAS(acc, g) do {                                                   \
        float bv0 = b_all[(g) * H_DIM + bn + wn + col];                         \
        float bv1 = b_all[(g) * H_DIM + bn + wn + 16 + col];                    \
        _Pragma("unroll") for (int mi = 0; mi < 2; ++mi) {                      \
            acc[mi][0] = (f32x4){bv0, bv0, bv0, bv0};                           \
            acc[mi][1] = (f32x4){bv1, bv1, bv1, bv1};                           \
        }                                                                       \
    } while (0)

    SET_BIAS(accA, 4); SET_BIAS(accB, 5);
    stage(Ax, WG(4), WG(5));
#pragma unroll
    for (int mi = 0; mi < 2; ++mi)
#pragma unroll
        for (int ni = 0; ni < 2; ++ni) { sm[mi][ni] = accA[mi][ni]; accA[mi][ni] = (f32x4){0,0,0,0}; }
    stage(Ah, UG(4), UG(5));
#pragma unroll
    for (int mi = 0; mi < 2; ++mi)
#pragma unroll
        for (int ni = 0; ni < 2; ++ni)
#pragma unroll
            for (int r = 0; r < 4; ++r)
                s1[mi][ni][r] = sigm(accB[mi][ni][r]) * (sm[mi][ni][r] * accA[mi][ni][r]);

    SET_BIAS(accA, 1); SET_BIAS(accB, 0);
    stage(Ax, WG(1), WG(0));
    stage(Ah, UG(1), UG(0));
#pragma unroll
    for (int mi = 0; mi < 2; ++mi)
#pragma unroll
        for (int ni = 0; ni < 2; ++ni)
#pragma unroll
            for (int r = 0; r < 4; ++r) {
                int rg = bm + wm + mi * 16 + rbase + r;
                int cg = bn + wn + ni * 16 + col;
                float cp = c_prev[(size_t)rg * H_DIM + cg];
                s2[mi][ni][r] = sigm(accA[mi][ni][r]) * cp + s1[mi][ni][r];
                s1[mi][ni][r] = sigm(accB[mi][ni][r]);
            }

    SET_BIAS(accA, 3); SET_BIAS(accB, 2);
    stage(Ax, WG(3), WG(2));
    stage(Ah, UG(3), UG(2));
#pragma unroll
    for (int mi = 0; mi < 2; ++mi)
#pragma unroll
        for (int ni = 0; ni < 2; ++ni)
#pragma unroll
            for (int r = 0; r < 4; ++r) {
                int rg = bm + wm + mi * 16 + rbase + r;
                int cg = bn + wn + ni * 16 + col;
                float cn = s2[mi][ni][r] + s1[mi][ni][r] * tanh_fast(accA[mi][ni][r]);
                float hv = sigm(accB[mi][ni][r]) * tanh_fast(cn);
                out[(size_t)rg * H_DIM + cg] = hv;
                out[(size_t)B_DIM * H_DIM + (size_t)rg * H_DIM + cg] = cn;
            }
#undef WG
#undef UG
#undef SET_BIAS
}

// ------------------------------------------- fallback 2 (round-2, fp32 in) ---
constexpr int FBM = 128, FBN = 128, FBK = 64;
constexpr int FLDS = FBK + 8;

__device__ __forceinline__ void f_mm_pass(const float* __restrict__ Ag,
                                          const float* __restrict__ Bg,
                                          unsigned short* lA, unsigned short* lB,
                                          int st_r, int st_c, int wm, int wn, int frow, int fk,
                                          f32x4 acc[4][2])
{
    for (int k0 = 0; k0 < K_DIM; k0 += FBK) {
#pragma unroll
        for (int q = 0; q < 4; ++q) {
            const int r = st_r + 32 * q;
            f32x4 av = *(const f32x4*)&Ag[(size_t)r * K_DIM + k0 + st_c];
            f32x4 bv = *(const f32x4*)&Bg[(size_t)r * K_DIM + k0 + st_c];
            u16x4 ap = { f2bf(av[0]), f2bf(av[1]), f2bf(av[2]), f2bf(av[3]) };
            u16x4 bp = { f2bf(bv[0]), f2bf(bv[1]), f2bf(bv[2]), f2bf(bv[3]) };
            *(u16x4*)&lA[r * FLDS + st_c] = ap;
            *(u16x4*)&lB[r * FLDS + st_c] = bp;
        }
        __syncthreads();
#pragma unroll
        for (int kk = 0; kk < FBK; kk += 32) {
            bf16x8 bfr0 = *(const bf16x8*)&lB[(wn      + frow) * FLDS + kk + fk];
            bf16x8 bfr1 = *(const bf16x8*)&lB[(wn + 16 + frow) * FLDS + kk + fk];
#pragma unroll
            for (int mi = 0; mi < 4; ++mi) {
                bf16x8 afr = *(const bf16x8*)&lA[(wm + mi * 16 + frow) * FLDS + kk + fk];
                acc[mi][0] = __builtin_amdgcn_mfma_f32_16x16x32_bf16(afr, bfr0, acc[mi][0], 0, 0, 0);
                acc[mi][1] = __builtin_amdgcn_mfma_f32_16x16x32_bf16(afr, bfr1, acc[mi][1], 0, 0, 0);
            }
        }
        __syncthreads();
    }
}

extern "C" __global__ __launch_bounds__(512, 2)
void xlstm_fused_f32(const float* __restrict__ x, const float* __restrict__ h_prev,
                     const float* __restrict__ c_prev, const float* __restrict__ W_all,
                     const float* __restrict__ b_all, const float* __restrict__ U_all,
                     float* __restrict__ out)
{
    __shared__ unsigned short lA[FBM * FLDS];
    __shared__ unsigned short lB[FBN * FLDS];
    const int tid = threadIdx.x;
    const int bm = blockIdx.y * FBM, bn = blockIdx.x * FBN;
    const int st_r = tid >> 4, st_c = (tid & 15) * 4;
    const int lane = tid & 63, wave = tid >> 6;
    const int wm = (wave & 1) * 64, wn = (wave >> 1) * 32;
    const int frow = lane & 15, fk = (lane >> 4) * 8;
    const int col = lane & 15, rbase = (lane >> 4) * 4;
    const float* Axt = x + (size_t)bm * K_DIM;
    const float* Aht = h_prev + (size_t)bm * K_DIM;
    f32x4 acc[4][2], s1[4][2], s2[4][2];
#define WGf(g) (W_all + (size_t)(g) * H_DIM * K_DIM + (size_t)bn * K_DIM)
#define UGf(g) (U_all + (size_t)(g) * H_DIM * H_DIM + (size_t)bn * H_DIM)
#define SET_BIASf(g) do {                                                       \
        float bv0 = b_all[(g) * H_DIM + bn + wn + col];                         \
        float bv1 = b_all[(g) * H_DIM + bn + wn + 16 + col];                    \
        _Pragma("unroll") for (int mi = 0; mi < 4; ++mi) {                      \
            acc[mi][0] = (f32x4){bv0, bv0, bv0, bv0};                           \
            acc[mi][1] = (f32x4){bv1, bv1, bv1, bv1};                           \
        }                                                                       \
    } while (0)
#define RUN_GATEf(g) do { SET_BIASf(g);                                         \
        f_mm_pass(Axt, WGf(g), lA, lB, st_r, st_c, wm, wn, frow, fk, acc);      \
        f_mm_pass(Aht, UGf(g), lA, lB, st_r, st_c, wm, wn, frow, fk, acc); } while (0)
    SET_BIASf(4);
    f_mm_pass(Axt, WGf(4), lA, lB, st_r, st_c, wm, wn, frow, fk, acc);
    for (int mi = 0; mi < 4; ++mi) for (int ni = 0; ni < 2; ++ni) s1[mi][ni] = acc[mi][ni];
    for (int mi = 0; mi < 4; ++mi) for (int ni = 0; ni < 2; ++ni) acc[mi][ni] = (f32x4){0,0,0,0};
    f_mm_pass(Aht, UGf(4), lA, lB, st_r, st_c, wm, wn, frow, fk, acc);
    for (int mi = 0; mi < 4; ++mi) for (int ni = 0; ni < 2; ++ni) s1[mi][ni] *= acc[mi][ni];
    RUN_GATEf(5);
    for (int mi = 0; mi < 4; ++mi) for (int ni = 0; ni < 2; ++ni)
        for (int r = 0; r < 4; ++r) s1[mi][ni][r] = sigm(acc[mi][ni][r]) * s1[mi][ni][r];
    RUN_GATEf(1);
    for (int mi = 0; mi < 4; ++mi) for (int ni = 0; ni < 2; ++ni)
        for (int r = 0; r < 4; ++r) {
            int rg = bm + wm + mi * 16 + rbase + r, cg = bn + wn + ni * 16 + col;
            s2[mi][ni][r] = sigm(acc[mi][ni][r]) * c_prev[(size_t)rg * H_DIM + cg] + s1[mi][ni][r];
        }
    RUN_GATEf(0);
    for (int mi = 0; mi < 4; ++mi) for (int ni = 0; ni < 2; ++ni)
        for (int r = 0; r < 4; ++r) s1[mi][ni][r] = sigm(acc[mi][ni][r]);
    RUN_GATEf(3);
    for (int mi = 0; mi < 4; ++mi) for (int ni = 0; ni < 2; ++ni)
        for (int r = 0; r < 4; ++r) s2[mi][ni][r] += s1[mi][ni][r] * tanh_fast(acc[mi][ni][r]);
    RUN_GATEf(2);
    for (int mi = 0; mi < 4; ++mi) for (int ni = 0; ni < 2; ++ni)
        for (int r = 0; r < 4; ++r) {
            int rg = bm + wm + mi * 16 + rbase + r, cg = bn + wn + ni * 16 + col;
            float cn = s2[mi][ni][r];
            out[(size_t)rg * H_DIM + cg] = sigm(acc[mi][ni][r]) * tanh_fast(cn);
            out[(size_t)B_DIM * H_DIM + (size_t)rg * H_DIM + cg] = cn;
        }
#undef WGf
#undef UGf
#undef SET_BIASf
#undef RUN_GATEf
}

// ------------------------------------------------------------------ launch ---
extern "C" void kernel_launch(void* const* d_in, const int* in_sizes, int n_in,
                              void* d_out, int out_size, void* d_ws, size_t ws_size,
                              hipStream_t stream)
{
    (void)in_sizes; (void)n_in; (void)out_size;
    const float* x      = (const float*)d_in[0];
    const float* h_prev = (const float*)d_in[1];
    const float* c_prev = (const float*)d_in[2];
    const float* W_all  = (const float*)d_in[3];
    const float* b_all  = (const float*)d_in[4];
    const float* U_all  = (const float*)d_in[5];
    float* out = (float*)d_out;

    const size_t need_z  = (WS_Z + 7 * ZPL) * 2ull;   // inputs + 7 z planes (bf16)
    const size_t need_r5 = WS_Z * 2ull;               // inputs only
    unsigned short* wsb = (unsigned short*)d_ws;

    if (ws_size >= need_z) {
        hipLaunchKernelGGL(cvt_all, dim3(2560), dim3(256), 0, stream,
                           x, h_prev, W_all, U_all, wsb);
        hipLaunchKernelGGL(gemm_z, dim3(48, 32), dim3(256), 0, stream,
                           wsb + WS_X, wsb + WS_H, wsb + WS_W, wsb + WS_U,
                           b_all, wsb + WS_Z);
        hipLaunchKernelGGL(combine, dim3(2048), dim3(256), 0, stream,
                           wsb + WS_Z, c_prev, out);
    } else if (ws_size >= need_r5) {
        hipLaunchKernelGGL(cvt_all, dim3(2560), dim3(256), 0, stream,
                           x, h_prev, W_all, U_all, wsb);
        hipLaunchKernelGGL(xlstm_main, dim3(H_DIM / BN, B_DIM / BM), dim3(512), 0, stream,
                           wsb + WS_X, wsb + WS_H, wsb + WS_W, wsb + WS_U,
                           b_all, c_prev, out);
    } else {
        hipLaunchKernelGGL(xlstm_fused_f32, dim3(H_DIM / FBN, B_DIM / FBM), dim3(512), 0, stream,
                           x, h_prev, c_prev, W_all, b_all, U_all, out);
    }
}